// Round 4
// baseline (363.278 us; speedup 1.0000x reference)
//
#include <hip/hip_runtime.h>

// Problem constants (from setup_inputs): B=4, H=384, W=512, C=64, fp32.
constexpr int B = 4, H = 384, W = 512, C = 64;
constexpr int HW = H * W;              // 196608
constexpr int C4 = C / 4;              // 16 float4 chunks per pixel
constexpr int BLOCKS_PER_IMG = HW * C4 / 256;  // 12288
constexpr int NXCD = 8;
constexpr int CHUNK = BLOCKS_PER_IMG / NXCD;   // 1536 (exact -> bijective swizzle)

typedef float f32x4 __attribute__((ext_vector_type(4)));
typedef float f32x2 __attribute__((ext_vector_type(2)));

// 16 consecutive threads handle one output pixel (one float4 of channels each):
// each bilinear tap is a contiguous 256 B row in feature -> fully coalesced.
// blockIdx.y = batch index. blockIdx.x is XCD-swizzled so each of the 8 XCDs
// streams a contiguous 48-row slab of the image: the bilinear reuse window
// (~±15 rows of flow spread × 128 KB/row ≈ 3.8 MB) then fits one 4 MB L2.
__global__ __launch_bounds__(256) void warp_kernel(
    const f32x2* __restrict__ flow,    // (B,H,W,2)
    const f32x4* __restrict__ feat,    // (B,H,W,C)
    const float* __restrict__ mask,    // (H,W)
    f32x4* __restrict__ out)           // (B,H,W,C)
{
    // XCD slab swizzle: hardware round-robins consecutive blockIdx.x across
    // XCDs; map (bx % 8) -> slab so XCD i owns rows [i*48, (i+1)*48).
    int bx   = blockIdx.x;
    int sbx  = (bx & (NXCD - 1)) * CHUNK + (bx >> 3);   // bijective (12288 % 8 == 0)
    int gid  = sbx * 256 + threadIdx.x;                 // over HW * C4
    int b    = blockIdx.y;
    int c4   = gid & (C4 - 1);
    int hw   = gid >> 4;
    int xg   = hw & (W - 1);     // W = 512 (pow2)
    int yg   = hw >> 9;
    int pix  = b * HW + hw;

    // flow (same value across the 16-lane group -> broadcast from cache)
    f32x2 f = flow[pix];
    float xt = (float)xg + f.x;
    float yt = (float)yg + f.y;

    // faithful to reference: x = (2*xt/(W-1) - 1 + 1) * 0.5 * W  (= xt * W/(W-1))
    float x = (2.0f * xt / (float)(W - 1)) * 0.5f * (float)W;
    float y = (2.0f * yt / (float)(H - 1)) * 0.5f * (float)H;

    // reference clamps the INT coords, then derives weights from the clamped values
    int x0 = min(max((int)floorf(x), 0), W - 1);
    int x1 = min(x0 + 1, W - 1);
    int y0 = min(max((int)floorf(y), 0), H - 1);
    int y1 = min(y0 + 1, H - 1);
    float x0f = (float)x0, x1f = (float)x1;
    float y0f = (float)y0, y1f = (float)y1;

    float wa = (x1f - x) * (y1f - y);
    float wb = (x1f - x) * (y - y0f);
    float wc = (x - x0f) * (y1f - y);
    float wd = (x - x0f) * (y - y0f);

    float m = mask[hw];

    int base = b * HW;
    f32x4 va = feat[(base + y0 * W + x0) * C4 + c4];
    f32x4 vb = feat[(base + y1 * W + x0) * C4 + c4];
    f32x4 vc = feat[(base + y0 * W + x1) * C4 + c4];
    f32x4 vd = feat[(base + y1 * W + x1) * C4 + c4];

    f32x4 r = (wa * va + wb * vb + wc * vc + wd * vd) * m;

    // Plain store (A/B vs round-3's nontemporal store, which may have
    // degraded the write path).
    out[pix * C4 + c4] = r;
}

extern "C" void kernel_launch(void* const* d_in, const int* in_sizes, int n_in,
                              void* d_out, int out_size, void* d_ws, size_t ws_size,
                              hipStream_t stream) {
    const f32x2* flow = (const f32x2*)d_in[0];   // w: (B,H,W,2)
    const f32x4* feat = (const f32x4*)d_in[1];   // feature: (B,H,W,C)
    const float* mask = (const float*)d_in[2];   // mask: (H,W)
    f32x4* out = (f32x4*)d_out;

    dim3 grid(BLOCKS_PER_IMG, B), block(256);
    warp_kernel<<<grid, block, 0, stream>>>(flow, feat, mask, out);
}

// Round 5
// 344.043 us; speedup vs baseline: 1.0559x; 1.0559x over previous
//
#include <hip/hip_runtime.h>

// Problem constants (from setup_inputs): B=4, H=384, W=512, C=64, fp32.
constexpr int B = 4, H = 384, W = 512, C = 64;
constexpr int HW = H * W;              // 196608
constexpr int C4 = C / 4;              // 16 float4 chunks per pixel
constexpr int BLOCKS_PER_IMG = HW * C4 / 256;  // 12288
constexpr int PF_ROWS = 40;  // prefetch distance: > max|flow| (~26 rows) + concurrency window

// Native clang vector types (required by __builtin_nontemporal_store).
typedef float f32x4 __attribute__((ext_vector_type(4)));
typedef float f32x2 __attribute__((ext_vector_type(2)));

// 16 consecutive threads per output pixel (one float4 of channels each): every
// bilinear tap is a contiguous 256 B row segment -> coalesced.
// Blocks dispatch in row-major order, so the grid forms a front marching down
// the image; each block densely prefetches the feature row PF_ROWS ahead of
// the front. The scattered bilinear gathers then hit L2/L3 instead of doing
// 64B-granule HBM reads (~1 TB/s effective — that was round 4's 129 µs).
__global__ __launch_bounds__(256) void warp_kernel(
    const f32x2* __restrict__ flow,    // (B,H,W,2)
    const f32x4* __restrict__ feat,    // (B,H,W,C)
    const float* __restrict__ mask,    // (H,W)
    f32x4* __restrict__ out)           // (B,H,W,C)
{
    int gid  = blockIdx.x * 256 + threadIdx.x;   // over HW * C4
    int b    = blockIdx.y;
    int c4   = gid & (C4 - 1);
    int hw   = gid >> 4;
    int xg   = hw & (W - 1);     // W = 512 (pow2)
    int yg   = hw >> 9;
    int base = b * HW;
    int pix  = base + hw;

    // Issue the dependent loads first (flow, mask), then the fire-and-forget
    // dense prefetch. vmcnt is an ordered queue, so waiting for flow leaves
    // the prefetch in flight.
    f32x2 f = flow[pix];
    float m = mask[hw];

    f32x4 pf = {};
    int pf_hw = hw + PF_ROWS * W;
    if (pf_hw < HW)                      // block-uniform branch (whole block = 1 row)
        pf = feat[(base + pf_hw) * C4 + c4];

    float xt = (float)xg + f.x;
    float yt = (float)yg + f.y;

    // == (2*xt/(W-1) - 1 + 1) * 0.5 * W, constant-folded to one multiply.
    // Bilinear interp is continuous across cell boundaries, so the ulp-level
    // deviation from the reference's div sequence is << the 0.125 tolerance.
    float x = xt * ((float)W / (float)(W - 1));
    float y = yt * ((float)H / (float)(H - 1));

    // reference clamps the INT coords, then derives weights from clamped values
    int x0 = min(max((int)floorf(x), 0), W - 1);
    int x1 = min(x0 + 1, W - 1);
    int y0 = min(max((int)floorf(y), 0), H - 1);
    int y1 = min(y0 + 1, H - 1);
    float x0f = (float)x0, x1f = (float)x1;
    float y0f = (float)y0, y1f = (float)y1;

    float wa = (x1f - x) * (y1f - y);
    float wb = (x1f - x) * (y - y0f);
    float wc = (x - x0f) * (y1f - y);
    float wd = (x - x0f) * (y - y0f);

    f32x4 va = feat[(base + y0 * W + x0) * C4 + c4];
    f32x4 vb = feat[(base + y1 * W + x0) * C4 + c4];
    f32x4 vc = feat[(base + y0 * W + x1) * C4 + c4];
    f32x4 vd = feat[(base + y1 * W + x1) * C4 + c4];

    f32x4 r = (wa * va + wb * vb + wc * vc + wd * vd) * m;

    // Keep the prefetch value live without storing it (prevents DCE).
    asm volatile("" :: "v"(pf));

    // Non-temporal: write-once output; don't evict the warmed feature window.
    __builtin_nontemporal_store(r, &out[pix * C4 + c4]);
}

extern "C" void kernel_launch(void* const* d_in, const int* in_sizes, int n_in,
                              void* d_out, int out_size, void* d_ws, size_t ws_size,
                              hipStream_t stream) {
    const f32x2* flow = (const f32x2*)d_in[0];   // w: (B,H,W,2)
    const f32x4* feat = (const f32x4*)d_in[1];   // feature: (B,H,W,C)
    const float* mask = (const float*)d_in[2];   // mask: (H,W)
    f32x4* out = (f32x4*)d_out;

    dim3 grid(BLOCKS_PER_IMG, B), block(256);
    warp_kernel<<<grid, block, 0, stream>>>(flow, feat, mask, out);
}